// Round 1
// 599.167 us; speedup vs baseline: 1.0028x; 1.0028x over previous
//
#include <hip/hip_runtime.h>

// ---------------------------------------------------------------------------
// BertAlibiUnpadSelfAttention on MI355X.
// K1 pack:  fp32 -> bf16 (hidden, Wqkv)
// K2 gemm:  qkv = hidden @ W^T + b  (bf16 MFMA 16x16x32, 128x128 tiles,
//           DOUBLE-BUFFERED global_load_lds staging, XCD-chunked swizzle)
// K3 attn:  flash-style online softmax; K/V LDS double-buffered, bias
//           register-prefetched one step ahead; setprio around MFMA.
// ---------------------------------------------------------------------------

typedef __attribute__((ext_vector_type(8))) short short8;
typedef __attribute__((ext_vector_type(4))) float floatx4;
typedef unsigned short u16;
typedef unsigned int u32;

#define LOG2E 1.4426950408889634f

__device__ __forceinline__ u16 f2bf(float f) {
  u32 u = __float_as_uint(f);
  u += 0x7FFFu + ((u >> 16) & 1u);   // round-to-nearest-even
  return (u16)(u >> 16);
}

typedef const __attribute__((address_space(1))) u32* gp_t;
typedef __attribute__((address_space(3))) u32* lp_t;
__device__ __forceinline__ void async_cp16(const void* g, void* l) {
  __builtin_amdgcn_global_load_lds((gp_t)g, (lp_t)l, 16, 0, 0);
}

// ------------------------------- K1: pack ----------------------------------
__global__ __launch_bounds__(256) void pack_kernel(
    const float* __restrict__ A, const float* __restrict__ W,
    u16* __restrict__ Abf, u16* __restrict__ Wbf) {
  unsigned u = blockIdx.x * 256u + threadIdx.x;  // 1,228,800 float4 units
  const unsigned nA = 786432u;                   // 4096*768/4
  float4 v;
  u16* dst;
  if (u < nA) { v = ((const float4*)A)[u]; dst = Abf + u * 4; }
  else        { unsigned q = u - nA; v = ((const float4*)W)[q]; dst = Wbf + q * 4; }
  ushort4 o;
  o.x = f2bf(v.x); o.y = f2bf(v.y); o.z = f2bf(v.z); o.w = f2bf(v.w);
  *(ushort4*)dst = o;
}

// ------------------------------- K2: qkv gemm ------------------------------
// C[m,n] = sum_k Abf[m,k]*Wbf[n,k] + bq[n];  M=4096 N=2304 K=768
// grid (18, 32) flattened + XCD-chunked swizzle. 256 thr = 4 waves (2x2 of 64x64).
// Double-buffered 8KB A/B tiles: issue kt+1 before computing kt; 1 barrier/kt.
__global__ __launch_bounds__(256, 3) void qkv_gemm(
    const u16* __restrict__ Abf, const u16* __restrict__ Wbf,
    const float* __restrict__ bq,
    u16* __restrict__ Qb, u16* __restrict__ Kb, u16* __restrict__ Vb) {
  __shared__ __align__(16) char smem[32768];
  char* As0 = smem;
  char* Bs0 = smem + 8192;
  char* As1 = smem + 16384;
  char* Bs1 = smem + 24576;
  const unsigned t = threadIdx.x;
  // XCD swizzle: nwg = 576, 576/8 = 72 contiguous per XCD
  unsigned orig = blockIdx.y * 18u + blockIdx.x;
  unsigned wg = (orig & 7u) * 72u + (orig >> 3);
  const unsigned nblk = wg % 18u, mblk = wg / 18u;
  const unsigned w = t >> 6, l = t & 63, quad = l >> 4, c = l & 15;
  const unsigned wm = (w >> 1) * 64, wn = (w & 1) * 64;

  floatx4 acc[4][4] = {};

  // staging: 8KB tile = 512 x 16B chunks; thread handles beta = t, t+256.
  const unsigned b0 = t, b1 = t + 256u;
  const unsigned r0 = b0 >> 2, ch0 = (b0 & 3u) ^ (r0 & 3u);
  const unsigned r1 = b1 >> 2, ch1 = (b1 & 3u) ^ (r1 & 3u);
  const char* gA0 = (const char*)Abf + (size_t)((mblk * 128 + r0) * 768) * 2 + ch0 * 16;
  const char* gA1 = (const char*)Abf + (size_t)((mblk * 128 + r1) * 768) * 2 + ch1 * 16;
  const char* gB0 = (const char*)Wbf + (size_t)((nblk * 128 + r0) * 768) * 2 + ch0 * 16;
  const char* gB1 = (const char*)Wbf + (size_t)((nblk * 128 + r1) * 768) * 2 + ch1 * 16;

  // prologue: stage kt=0 into buffer 0
  async_cp16(gA0, As0 + b0 * 16);
  async_cp16(gA1, As0 + b1 * 16);
  async_cp16(gB0, Bs0 + b0 * 16);
  async_cp16(gB1, Bs0 + b1 * 16);
  __syncthreads();

  for (unsigned kt = 0; kt < 24; ++kt) {
    char* Ac = (kt & 1u) ? As1 : As0;
    char* Bc = (kt & 1u) ? Bs1 : Bs0;
    if (kt + 1 < 24) {
      char* An = (kt & 1u) ? As0 : As1;
      char* Bn = (kt & 1u) ? Bs0 : Bs1;
      async_cp16(gA0 + (kt + 1) * 64, An + b0 * 16);
      async_cp16(gA1 + (kt + 1) * 64, An + b1 * 16);
      async_cp16(gB0 + (kt + 1) * 64, Bn + b0 * 16);
      async_cp16(gB1 + (kt + 1) * 64, Bn + b1 * 16);
    }
    short8 af[4], bf[4];
#pragma unroll
    for (int mt = 0; mt < 4; ++mt) {
      unsigned row = wm + mt * 16 + c;
      af[mt] = *(const short8*)(Ac + row * 64 + 16 * (quad ^ (row & 3u)));
    }
#pragma unroll
    for (int nt = 0; nt < 4; ++nt) {
      unsigned row = wn + nt * 16 + c;
      bf[nt] = *(const short8*)(Bc + row * 64 + 16 * (quad ^ (row & 3u)));
    }
#pragma unroll
    for (int mt = 0; mt < 4; ++mt)
#pragma unroll
      for (int nt = 0; nt < 4; ++nt)
        acc[mt][nt] = __builtin_amdgcn_mfma_f32_16x16x32_bf16(af[mt], bf[nt], acc[mt][nt], 0, 0, 0);
    __syncthreads();  // drains vmcnt: next buffer is fully staged after this
  }

  // epilogue: + bias, route to Q/K/V^T bf16.
  float bqv[4];
#pragma unroll
  for (int nt = 0; nt < 4; ++nt) bqv[nt] = bq[nblk * 128 + wn + nt * 16 + c];
#pragma unroll
  for (int mt = 0; mt < 4; ++mt) {
#pragma unroll
    for (int r = 0; r < 4; ++r) {
      unsigned m = mblk * 128 + wm + mt * 16 + quad * 4 + r;
      unsigned bb = m >> 11, s = m & 2047u;
#pragma unroll
      for (int nt = 0; nt < 4; ++nt) {
        float val = acc[mt][nt][r] + bqv[nt];
        unsigned n = nblk * 128 + wn + nt * 16 + c;
        u16 bv = f2bf(val);
        if (n < 768u) {
          unsigned h = n >> 6, d = n & 63u;
          Qb[(((bb * 12 + h) * 2048 + s) << 6) + d] = bv;
        } else if (n < 1536u) {
          unsigned n2 = n - 768u, h = n2 >> 6, d = n2 & 63u;
          Kb[(((bb * 12 + h) * 2048 + s) << 6) + d] = bv;
        } else {
          unsigned n2 = n - 1536u, h = n2 >> 6, d = n2 & 63u;
          Vb[(((bb * 12 + h) << 6) + d) * 2048 + s] = bv;
        }
      }
    }
  }
}

// ------------------------------- K3: attention -----------------------------
// grid = 768 blocks (XCD-chunked): bh (24) x qt (32 q-tiles of 64 rows).
// K/V tiles double-buffered in LDS; bias tile prefetched one step ahead into
// registers; ONE barrier per step; setprio(1) around MFMA clusters.
__global__ __launch_bounds__(256, 3) void attn_kernel(
    const u16* __restrict__ Qb, const u16* __restrict__ Kb,
    const u16* __restrict__ Vb, const float* __restrict__ bias,
    float* __restrict__ out) {
  __shared__ __align__(16) char smem[49152];
  char* Qs  = smem;            // 8KB: 64 q-rows x 128B
  char* Ks0 = smem + 8192;     // 8KB dbuf A
  char* Ks1 = smem + 16384;    // 8KB dbuf B
  char* Vs0 = smem + 24576;    // 8KB dbuf A (V^T)
  char* Vs1 = smem + 32768;    // 8KB dbuf B
  char* Ps  = smem + 40960;    // 8KB: 4 waves x (16 q x 128B)
  const unsigned t = threadIdx.x;
  // XCD swizzle: nwg = 768, 96 contiguous per XCD -> 3 bh slabs per XCD L2
  unsigned wgid = (blockIdx.x & 7u) * 96u + (blockIdx.x >> 3);
  const unsigned bh = wgid >> 5, qt = wgid & 31u;
  const unsigned q0 = qt * 64;
  const unsigned w = t >> 6, l = t & 63, quad = l >> 4, c = l & 15;

  const unsigned b0 = t, b1 = t + 256u;
  const unsigned r0 = b0 >> 3, ch0 = (b0 & 7u) ^ (r0 & 7u);
  const unsigned r1 = b1 >> 3, ch1 = (b1 & 7u) ^ (r1 & 7u);

  const char* gK0 = (const char*)Kb + (size_t)(bh * 2048 + r0) * 128 + ch0 * 16;
  const char* gK1 = (const char*)Kb + (size_t)(bh * 2048 + r1) * 128 + ch1 * 16;
  const char* gV0 = (const char*)Vb + (size_t)(bh * 64 + r0) * 4096 + ch0 * 16;
  const char* gV1 = (const char*)Vb + (size_t)(bh * 64 + r1) * 4096 + ch1 * 16;
  const float* bias_base = bias + (size_t)(bh * 2048 + q0 + w * 16 + quad * 4) * 2048 + c;
  const unsigned pb = w * 2048u;  // this wave's P region

  // prologue: stage Q + K/V tile 0, prefetch bias tile 0 into registers
  async_cp16((const char*)Qb + (size_t)(bh * 2048 + q0 + r0) * 128 + ch0 * 16, Qs + b0 * 16);
  async_cp16((const char*)Qb + (size_t)(bh * 2048 + q0 + r1) * 128 + ch1 * 16, Qs + b1 * 16);
  async_cp16(gK0, Ks0 + b0 * 16);
  async_cp16(gK1, Ks0 + b1 * 16);
  async_cp16(gV0, Vs0 + b0 * 16);
  async_cp16(gV1, Vs0 + b1 * 16);
  float bvA[4][4], bvB[4][4];
#pragma unroll
  for (int tt = 0; tt < 4; ++tt)
#pragma unroll
    for (int r = 0; r < 4; ++r)
      bvA[tt][r] = bias_base[(size_t)r * 2048 + tt * 16];
  __syncthreads();

  short8 aq[2];
  {
    unsigned row = w * 16 + c;          // A-frag: m = lane&15
    aq[0] = *(const short8*)(Qs + row * 128 + 16 * ((quad + 0u) ^ (row & 7u)));
    aq[1] = *(const short8*)(Qs + row * 128 + 16 * ((quad + 4u) ^ (row & 7u)));
  }

  float mrun[4] = {-1e30f, -1e30f, -1e30f, -1e30f};
  float lrun[4] = {0.f, 0.f, 0.f, 0.f};
  floatx4 oacc[4] = {};

  for (unsigned tix = 0; tix < 32; ++tix) {
    const unsigned k0 = tix * 64u;
    const char* Kc = (tix & 1u) ? Ks1 : Ks0;
    const char* Vc = (tix & 1u) ? Vs1 : Vs0;

    // issue next tile's global loads BEFORE compute (latency hides under step)
    if (tix + 1 < 32) {
      char* Kn = (tix & 1u) ? Ks0 : Ks1;
      char* Vn = (tix & 1u) ? Vs0 : Vs1;
      async_cp16(gK0 + (size_t)(k0 + 64) * 128, Kn + b0 * 16);
      async_cp16(gK1 + (size_t)(k0 + 64) * 128, Kn + b1 * 16);
      async_cp16(gV0 + (size_t)(k0 + 64) * 2, Vn + b0 * 16);
      async_cp16(gV1 + (size_t)(k0 + 64) * 2, Vn + b1 * 16);
#pragma unroll
      for (int tt = 0; tt < 4; ++tt)
#pragma unroll
        for (int r = 0; r < 4; ++r)
          bvB[tt][r] = bias_base[(size_t)r * 2048 + (k0 + 64) + tt * 16];
    }

    // S = Q K^T  (from current buffer)
    floatx4 s4[4] = {};
    __builtin_amdgcn_s_setprio(1);
#pragma unroll
    for (int ds = 0; ds < 2; ++ds)
#pragma unroll
      for (int tt = 0; tt < 4; ++tt) {
        unsigned row = tt * 16 + c;  // B-frag: n = lane&15 (key)
        short8 kf = *(const short8*)(Kc + row * 128 + 16 * (((unsigned)quad + 4u * ds) ^ (c & 7u)));
        s4[tt] = __builtin_amdgcn_mfma_f32_16x16x32_bf16(aq[ds], kf, s4[tt], 0, 0, 0);
      }
    __builtin_amdgcn_s_setprio(0);

    // online softmax (base-2): x = (dot + 8*bias) * log2e/8 ; bias from regs
    float alpha[4];
    float pr[4][4];
#pragma unroll
    for (int r = 0; r < 4; ++r) {
      float x0 = fmaf(bvA[0][r], 8.0f, s4[0][r]) * (LOG2E / 8.0f);
      float x1 = fmaf(bvA[1][r], 8.0f, s4[1][r]) * (LOG2E / 8.0f);
      float x2 = fmaf(bvA[2][r], 8.0f, s4[2][r]) * (LOG2E / 8.0f);
      float x3 = fmaf(bvA[3][r], 8.0f, s4[3][r]) * (LOG2E / 8.0f);
      float mx = fmaxf(fmaxf(x0, x1), fmaxf(x2, x3));
      mx = fmaxf(mx, __shfl_xor(mx, 1));
      mx = fmaxf(mx, __shfl_xor(mx, 2));
      mx = fmaxf(mx, __shfl_xor(mx, 4));
      mx = fmaxf(mx, __shfl_xor(mx, 8));
      float mn = fmaxf(mrun[r], mx);
      float a = __builtin_amdgcn_exp2f(mrun[r] - mn);
      mrun[r] = mn;
      float p0 = __builtin_amdgcn_exp2f(x0 - mn);
      float p1 = __builtin_amdgcn_exp2f(x1 - mn);
      float p2 = __builtin_amdgcn_exp2f(x2 - mn);
      float p3 = __builtin_amdgcn_exp2f(x3 - mn);
      pr[0][r] = p0; pr[1][r] = p1; pr[2][r] = p2; pr[3][r] = p3;
      float rs = (p0 + p1) + (p2 + p3);
      rs += __shfl_xor(rs, 1);
      rs += __shfl_xor(rs, 2);
      rs += __shfl_xor(rs, 4);
      rs += __shfl_xor(rs, 8);
      lrun[r] = lrun[r] * a + rs;
      alpha[r] = a;
    }
#pragma unroll
    for (int dt = 0; dt < 4; ++dt) {
      oacc[dt][0] *= alpha[0]; oacc[dt][1] *= alpha[1];
      oacc[dt][2] *= alpha[2]; oacc[dt][3] *= alpha[3];
    }

    // P (C-layout) -> LDS (A-operand layout), wave-private
#pragma unroll
    for (int tt = 0; tt < 4; ++tt)
#pragma unroll
      for (int r = 0; r < 4; ++r) {
        unsigned qq = quad * 4 + r;
        unsigned off = pb + qq * 128 + 16 * (((unsigned)(2 * tt) + (c >> 3)) ^ (qq & 7u)) + 2 * (c & 7u);
        *(u16*)(Ps + off) = f2bf(pr[tt][r]);
      }
    asm volatile("s_waitcnt lgkmcnt(0)" ::: "memory");

    // O += P V (from current buffer)
    __builtin_amdgcn_s_setprio(1);
#pragma unroll
    for (int js = 0; js < 2; ++js) {
      short8 pf = *(const short8*)(Ps + pb + (l & 15) * 128 +
                                   16 * (((unsigned)quad + 4u * js) ^ ((l & 15) & 7u)));
#pragma unroll
      for (int dt = 0; dt < 4; ++dt) {
        unsigned row = dt * 16 + c;  // V^T row = d
        short8 vf = *(const short8*)(Vc + row * 128 + 16 * (((unsigned)quad + 4u * js) ^ (c & 7u)));
        oacc[dt] = __builtin_amdgcn_mfma_f32_16x16x32_bf16(pf, vf, oacc[dt], 0, 0, 0);
      }
    }
    __builtin_amdgcn_s_setprio(0);

    // one barrier per step: drains our prefetch (vmcnt) + joins waves so the
    // buffer we read this step can be overwritten next step.
    __syncthreads();

    if (tix + 1 < 32) {
#pragma unroll
      for (int tt = 0; tt < 4; ++tt)
#pragma unroll
        for (int r = 0; r < 4; ++r)
          bvA[tt][r] = bvB[tt][r];
    }
  }

  // epilogue: out[(b*2048+q)*768 + h*64 + d] = O / l   (identity unpad)
  unsigned b_ = bh / 12u, h = bh % 12u;
#pragma unroll
  for (int r = 0; r < 4; ++r) {
    float li = 1.0f / lrun[r];
    unsigned qg = q0 + w * 16 + quad * 4 + r;
    float* op = out + (size_t)(b_ * 2048 + qg) * 768 + h * 64 + c;
#pragma unroll
    for (int dt = 0; dt < 4; ++dt) op[dt * 16] = oacc[dt][r] * li;
  }
}

// ------------------------------- launch ------------------------------------
extern "C" void kernel_launch(void* const* d_in, const int* in_sizes, int n_in,
                              void* d_out, int out_size, void* d_ws, size_t ws_size,
                              hipStream_t stream) {
  const float* hidden = (const float*)d_in[0];   // 4096 x 768
  const float* Wqkv_w = (const float*)d_in[1];   // 2304 x 768
  const float* Wqkv_b = (const float*)d_in[2];   // 2304
  const float* bias   = (const float*)d_in[3];   // 2 x 12 x 2048 x 2048
  float* out = (float*)d_out;

  char* ws = (char*)d_ws;
  u16* Abf = (u16*)(ws);                 //  6,291,456 B
  u16* Wbf = (u16*)(ws + 6291456);       //  3,538,944 B
  u16* Qb  = (u16*)(ws + 9830400);       //  6,291,456 B
  u16* Kb  = (u16*)(ws + 16121856);      //  6,291,456 B
  u16* Vb  = (u16*)(ws + 22413312);      //  6,291,456 B  (total ~27.4 MB)

  pack_kernel<<<4800, 256, 0, stream>>>(hidden, Wqkv_w, Abf, Wbf);
  qkv_gemm<<<dim3(18, 32), 256, 0, stream>>>(Abf, Wbf, Wqkv_b, Qb, Kb, Vb);
  attn_kernel<<<768, 256, 0, stream>>>(Qb, Kb, Vb, bias, out);
}